// Round 7
// baseline (647.495 us; speedup 1.0000x reference)
//
#include <hip/hip_runtime.h>
#include <hip/hip_fp16.h>
#include <math.h>

// ---------------------------------------------------------------------------
// ADCGNN amazon: N=50000, E=1.6M, IN=128, H=64, C=2, K=3
// fp16 AoS gather tables (row = 64 halves = 128 B): hs=h*dinv, u1s=u1*dinv,
// u2 direct. h/u1 recovered via rdeg=sqrt(deg). All per-node dense kernels
// use 4 threads/node (3128 waves -> real TLP; lesson from R6: serial
// per-wave chains at 780 waves never hide latency).
//
//   build: bucket_count -> bucket_scan -> bucket_scatter -> csr_build
//   dense1: h1 = relu(X@W1+b1)          fp32 AoS   (4 thr/node)
//   dense2: hs16 = relu(h1@W2+b2)*dinv  fp16 AoS   (4 thr/node)
//   spmm:   u1s16 = dinv^2 * (A^T hs16)            (wave/node)
//   spmm2:  u2_16 = dinv   * (A^T u1s16)           (wave/node)
//   mlp:    4 thr/node: scores (full dots) -> softmax -> res GEMV (LDS
//           exchange) -> Wf1/Wf2 -> W3 -> W4 -> logits
// ---------------------------------------------------------------------------

#define BSHIFT 7
#define BNODES 128
#define BMAX   512
#define EPT    32
#define CHUNK  (256 * EPT)
#define CAP    8192

__device__ __forceinline__ void fma4(float4& acc, float s, const float4 w) {
    acc.x += s * w.x; acc.y += s * w.y; acc.z += s * w.z; acc.w += s * w.w;
}
__device__ __forceinline__ void acc_h8(float4& a, float4& b, const float4 v) {
    const __half2* hp = (const __half2*)&v;
    float2 f0 = __half22float2(hp[0]);
    float2 f1 = __half22float2(hp[1]);
    float2 f2 = __half22float2(hp[2]);
    float2 f3 = __half22float2(hp[3]);
    a.x += f0.x; a.y += f0.y; a.z += f1.x; a.w += f1.y;
    b.x += f2.x; b.y += f2.y; b.z += f3.x; b.w += f3.y;
}
__device__ __forceinline__ float4 pack_h8(const float* v, float s) {
    float4 o;
    __half2* hp = (__half2*)&o;
    hp[0] = __floats2half2_rn(v[0] * s, v[1] * s);
    hp[1] = __floats2half2_rn(v[2] * s, v[3] * s);
    hp[2] = __floats2half2_rn(v[4] * s, v[5] * s);
    hp[3] = __floats2half2_rn(v[6] * s, v[7] * s);
    return o;
}
__device__ __forceinline__ void unp8(const float4 v, float* f) {
    const __half2* hp = (const __half2*)&v;
    float2 a = __half22float2(hp[0]); f[0] = a.x; f[1] = a.y;
    float2 b = __half22float2(hp[1]); f[2] = b.x; f[3] = b.y;
    float2 c = __half22float2(hp[2]); f[4] = c.x; f[5] = c.y;
    float2 d = __half22float2(hp[3]); f[6] = d.x; f[7] = d.y;
}

// ----------------------------- graph build ---------------------------------

__global__ __launch_bounds__(256) void bucket_count_k(const int* __restrict__ dst,
                                                      int* __restrict__ bucketCount,
                                                      int E, int B) {
    __shared__ int cnt[BMAX];
    for (int i = threadIdx.x; i < B; i += 256) cnt[i] = 0;
    __syncthreads();
    int base = blockIdx.x * CHUNK;
    #pragma unroll
    for (int t = 0; t < EPT; t++) {
        int e = base + t * 256 + threadIdx.x;
        if (e < E) atomicAdd(&cnt[dst[e] >> BSHIFT], 1);
    }
    __syncthreads();
    for (int i = threadIdx.x; i < B; i += 256)
        if (cnt[i] > 0) atomicAdd(&bucketCount[i], cnt[i]);
}

__global__ __launch_bounds__(64) void bucket_scan_k(const int* __restrict__ bucketCount,
                                                    int* __restrict__ bucketPtr,
                                                    int* __restrict__ bucketCursor,
                                                    int* __restrict__ rowPtr,
                                                    int B, int N, int E) {
    int lane = threadIdx.x;
    const int PT = (BMAX + 63) / 64;
    int v[PT]; int s = 0;
    #pragma unroll
    for (int t = 0; t < PT; t++) {
        int i = lane * PT + t;
        v[t] = (i < B) ? bucketCount[i] : 0;
        s += v[t];
    }
    int x = s;
    #pragma unroll
    for (int off = 1; off < 64; off <<= 1) {
        int y = __shfl_up(x, off, 64);
        if (lane >= off) x += y;
    }
    int run = x - s;
    #pragma unroll
    for (int t = 0; t < PT; t++) {
        int i = lane * PT + t;
        if (i < B) { bucketPtr[i] = run; bucketCursor[i] = run; }
        run += v[t];
    }
    if (lane == 63) bucketPtr[B] = x;
    if (lane == 0) rowPtr[N] = E;
}

__global__ __launch_bounds__(256) void bucket_scatter_k(const int* __restrict__ src,
                                                        const int* __restrict__ dst,
                                                        int* __restrict__ bucketCursor,
                                                        int* __restrict__ ebuf,
                                                        int E, int B) {
    __shared__ int cnt[BMAX];
    __shared__ int base[BMAX];
    __shared__ int cur[BMAX];
    for (int i = threadIdx.x; i < B; i += 256) { cnt[i] = 0; cur[i] = 0; }
    __syncthreads();
    int cbase = blockIdx.x * CHUNK;
    int d[EPT];
    #pragma unroll
    for (int t = 0; t < EPT; t++) {
        int e = cbase + t * 256 + threadIdx.x;
        d[t] = (e < E) ? dst[e] : -1;
        if (d[t] >= 0) atomicAdd(&cnt[d[t] >> BSHIFT], 1);
    }
    __syncthreads();
    for (int i = threadIdx.x; i < B; i += 256)
        if (cnt[i] > 0) base[i] = atomicAdd(&bucketCursor[i], cnt[i]);
    __syncthreads();
    #pragma unroll
    for (int t = 0; t < EPT; t++) {
        int e = cbase + t * 256 + threadIdx.x;
        if (d[t] >= 0) {
            int b = d[t] >> BSHIFT;
            int c = atomicAdd(&cur[b], 1);
            int pack = (src[e] & 0xFFFF) | ((d[t] & (BNODES - 1)) << 16);
            ebuf[base[b] + c] = pack;
        }
    }
}

__global__ __launch_bounds__(256) void csr_build_k(const int* __restrict__ ebuf,
                                                   const int* __restrict__ bucketPtr,
                                                   int* __restrict__ rowPtr,
                                                   float* __restrict__ dinv,
                                                   float* __restrict__ rdeg,
                                                   int* __restrict__ srcSorted,
                                                   int N) {
    __shared__ int deg[BNODES];
    __shared__ int rp[BNODES + 1];
    __shared__ int cur[BNODES];
    __shared__ int stage[CAP];
    int b = blockIdx.x;
    int nodeBase = b << BSHIFT;
    int nNodes = min(BNODES, N - nodeBase);
    int eBase = bucketPtr[b];
    int eCnt = bucketPtr[b + 1] - eBase;
    for (int i = threadIdx.x; i < BNODES; i += 256) deg[i] = 0;
    __syncthreads();
    for (int i = threadIdx.x; i < eCnt; i += 256)
        atomicAdd(&deg[(ebuf[eBase + i] >> 16) & (BNODES - 1)], 1);
    __syncthreads();
    if (threadIdx.x < 64) {
        int lane = threadIdx.x;
        int d0 = deg[2 * lane], d1 = deg[2 * lane + 1];
        int s = d0 + d1;
        int x = s;
        #pragma unroll
        for (int off = 1; off < 64; off <<= 1) {
            int y = __shfl_up(x, off, 64);
            if (lane >= off) x += y;
        }
        int ex = x - s;
        rp[2 * lane] = ex;
        rp[2 * lane + 1] = ex + d0;
        cur[2 * lane] = ex;
        cur[2 * lane + 1] = ex + d0;
        if (lane == 63) rp[BNODES] = x;
    }
    __syncthreads();
    for (int j = threadIdx.x; j < nNodes; j += 256) {
        rowPtr[nodeBase + j] = eBase + rp[j];
        int dg = deg[j];
        float d = (float)(dg > 1 ? dg : 1);
        dinv[nodeBase + j] = rsqrtf(d);
        rdeg[nodeBase + j] = sqrtf(d);
    }
    if (eCnt <= CAP) {
        for (int i = threadIdx.x; i < eCnt; i += 256) {
            int p = ebuf[eBase + i];
            int ld = (p >> 16) & (BNODES - 1);
            int pos = atomicAdd(&cur[ld], 1);
            stage[pos] = p & 0xFFFF;
        }
        __syncthreads();
        for (int i = threadIdx.x; i < eCnt; i += 256)
            srcSorted[eBase + i] = stage[i];
    } else {
        for (int i = threadIdx.x; i < eCnt; i += 256) {
            int p = ebuf[eBase + i];
            int ld = (p >> 16) & (BNODES - 1);
            int pos = atomicAdd(&cur[ld], 1);
            srcSorted[eBase + pos] = p & 0xFFFF;
        }
    }
}

// ----------------------------- dense1 (4 thr/node) -------------------------
// t = n*4+sub; sub owns 16 output cols. X row loads: 4 lanes share address
// (coalesced to 256 B/inst). Weights per-k 64 B/inst from L1.

__global__ __launch_bounds__(256) void dense1_k(const float* __restrict__ Xg,
                                                const float* __restrict__ W1,
                                                const float* __restrict__ b1,
                                                float* __restrict__ h1, int N) {
    int t = blockIdx.x * 256 + threadIdx.x;
    int n = t >> 2, sub = t & 3;
    if (n >= N) return;
    const float4* X = (const float4*)Xg + (size_t)n * 32;
    const float4* Wp = (const float4*)W1 + sub * 4;   // row stride 16 float4
    const float4* Bp = (const float4*)b1 + sub * 4;
    float4 acc[4] = {Bp[0], Bp[1], Bp[2], Bp[3]};
    #pragma unroll 4
    for (int kc = 0; kc < 32; kc++) {
        float4 a = X[kc];
        const float4* w0 = Wp + (4 * kc) * 16;
        const float4* w1 = Wp + (4 * kc + 1) * 16;
        const float4* w2 = Wp + (4 * kc + 2) * 16;
        const float4* w3 = Wp + (4 * kc + 3) * 16;
        #pragma unroll
        for (int i = 0; i < 4; i++) {
            fma4(acc[i], a.x, w0[i]);
            fma4(acc[i], a.y, w1[i]);
            fma4(acc[i], a.z, w2[i]);
            fma4(acc[i], a.w, w3[i]);
        }
    }
    float4* O = (float4*)h1 + (size_t)n * 16 + sub * 4;
    #pragma unroll
    for (int i = 0; i < 4; i++) {
        float4 v = acc[i];
        O[i] = make_float4(fmaxf(v.x, 0.f), fmaxf(v.y, 0.f),
                           fmaxf(v.z, 0.f), fmaxf(v.w, 0.f));
    }
}

// ----------------------------- dense2 (4 thr/node) -------------------------
// hs16 = relu(h1@W2+b2)*dinv, fp16 out (sub writes 32 B slice).

__global__ __launch_bounds__(256) void dense2_k(const float* __restrict__ h1,
                                                const float* __restrict__ W2,
                                                const float* __restrict__ b2,
                                                const float* __restrict__ dinv,
                                                float4* __restrict__ hs16, int N) {
    int t = blockIdx.x * 256 + threadIdx.x;
    int n = t >> 2, sub = t & 3;
    if (n >= N) return;
    const float4* X = (const float4*)h1 + (size_t)n * 16;
    const float4* Wp = (const float4*)W2 + sub * 4;
    const float4* Bp = (const float4*)b2 + sub * 4;
    float4 acc[4] = {Bp[0], Bp[1], Bp[2], Bp[3]};
    #pragma unroll 4
    for (int kc = 0; kc < 16; kc++) {
        float4 a = X[kc];
        const float4* w0 = Wp + (4 * kc) * 16;
        const float4* w1 = Wp + (4 * kc + 1) * 16;
        const float4* w2 = Wp + (4 * kc + 2) * 16;
        const float4* w3 = Wp + (4 * kc + 3) * 16;
        #pragma unroll
        for (int i = 0; i < 4; i++) {
            fma4(acc[i], a.x, w0[i]);
            fma4(acc[i], a.y, w1[i]);
            fma4(acc[i], a.z, w2[i]);
            fma4(acc[i], a.w, w3[i]);
        }
    }
    float f[16];
    #pragma unroll
    for (int i = 0; i < 4; i++) {
        f[4 * i + 0] = fmaxf(acc[i].x, 0.f);
        f[4 * i + 1] = fmaxf(acc[i].y, 0.f);
        f[4 * i + 2] = fmaxf(acc[i].z, 0.f);
        f[4 * i + 3] = fmaxf(acc[i].w, 0.f);
    }
    float di = dinv[n];
    hs16[(size_t)n * 8 + sub * 2 + 0] = pack_h8(&f[0], di);
    hs16[(size_t)n * 8 + sub * 2 + 1] = pack_h8(&f[8], di);
}

// ----------------------------- SPMM gathers (fp16) -------------------------
// Wave per node; lane = sub(0..7)*8 + q(0..7); 8 rows per load inst.

template <bool SQ>
__global__ __launch_bounds__(256) void spmm_k(const float4* __restrict__ xs16,
                                              const int* __restrict__ srcs,
                                              const int* __restrict__ rowPtr,
                                              const float* __restrict__ dinv,
                                              float4* __restrict__ out16, int N) {
    int node = (blockIdx.x * 256 + threadIdx.x) >> 6;
    if (node >= N) return;
    int lane = threadIdx.x & 63;
    int sub = lane >> 3, q = lane & 7;
    int s0 = rowPtr[node], s1 = rowPtr[node + 1];
    float4 z = make_float4(0.f, 0.f, 0.f, 0.f);
    float4 a0 = z, a1 = z, b0 = z, b1 = z, c0 = z, c1 = z, d0 = z, d1 = z;
    int i = s0 + sub;
    for (; i + 24 < s1; i += 32) {
        float4 vA = xs16[(size_t)srcs[i] * 8 + q];
        float4 vB = xs16[(size_t)srcs[i + 8] * 8 + q];
        float4 vC = xs16[(size_t)srcs[i + 16] * 8 + q];
        float4 vD = xs16[(size_t)srcs[i + 24] * 8 + q];
        acc_h8(a0, a1, vA); acc_h8(b0, b1, vB);
        acc_h8(c0, c1, vC); acc_h8(d0, d1, vD);
    }
    for (; i < s1; i += 8) {
        float4 v = xs16[(size_t)srcs[i] * 8 + q];
        acc_h8(a0, a1, v);
    }
    a0.x += b0.x + c0.x + d0.x; a0.y += b0.y + c0.y + d0.y;
    a0.z += b0.z + c0.z + d0.z; a0.w += b0.w + c0.w + d0.w;
    a1.x += b1.x + c1.x + d1.x; a1.y += b1.y + c1.y + d1.y;
    a1.z += b1.z + c1.z + d1.z; a1.w += b1.w + c1.w + d1.w;
    #pragma unroll
    for (int m = 8; m < 64; m <<= 1) {
        a0.x += __shfl_xor(a0.x, m, 64); a0.y += __shfl_xor(a0.y, m, 64);
        a0.z += __shfl_xor(a0.z, m, 64); a0.w += __shfl_xor(a0.w, m, 64);
        a1.x += __shfl_xor(a1.x, m, 64); a1.y += __shfl_xor(a1.y, m, 64);
        a1.z += __shfl_xor(a1.z, m, 64); a1.w += __shfl_xor(a1.w, m, 64);
    }
    if (sub == 0) {
        float di = dinv[node];
        float s = SQ ? di * di : di;
        float f[8] = {a0.x, a0.y, a0.z, a0.w, a1.x, a1.y, a1.z, a1.w};
        out16[(size_t)node * 8 + q] = pack_h8(f, s);
    }
}

// ----------------------------- fused MLP tail (4 thr/node) -----------------
// Per block: 64 nodes. Phase1: res GEMV slice (-> LDS) + full-dot scores.
// Phase2: Wf1 GEMV slice -> fw (quad reduce). Phase3: W3 GEMV slice using
// LDS res row -> W4 partial -> quad reduce -> out. Node rows (fp16, 128 B)
// re-read per phase; block working set 24 KB fits L1.

#define ML_PAD 68

__global__ __launch_bounds__(256) void mlp_k(const float4* __restrict__ hs16,
                                             const float4* __restrict__ u1s16,
                                             const float4* __restrict__ u2s16,
                                             const float* __restrict__ rdeg,
                                             const float* __restrict__ Wattn,
                                             const float* __restrict__ battn,
                                             const float* __restrict__ Wres,
                                             const float* __restrict__ bres,
                                             const float* __restrict__ Wf1,
                                             const float* __restrict__ bf1,
                                             const float* __restrict__ Wf2,
                                             const float* __restrict__ bf2,
                                             const float* __restrict__ W3,
                                             const float* __restrict__ b3,
                                             const float* __restrict__ W4,
                                             const float* __restrict__ b4,
                                             float2* __restrict__ out, int N) {
    __shared__ float ldsres[64 * ML_PAD];
    int t = blockIdx.x * 256 + threadIdx.x;
    int n = t >> 2, sub = t & 3;
    int nl = threadIdx.x >> 2;
    bool act = (n < N);
    const float4* hr = hs16 + (size_t)(act ? n : 0) * 8;
    const float4* u1r = u1s16 + (size_t)(act ? n : 0) * 8;
    const float4* u2r = u2s16 + (size_t)(act ? n : 0) * 8;
    float rd = act ? rdeg[n] : 0.f;
    // ---- phase 1: res slice + scores (full dots, no reduce needed) ----
    const float4* WR = (const float4*)Wres;
    const float4* BR = (const float4*)bres + sub * 4;
    float4 racc[4] = {BR[0], BR[1], BR[2], BR[3]};
    float th = 0.f, ta = 0.f, tb = 0.f;
    #pragma unroll 2
    for (int c = 0; c < 8; c++) {
        float hf[8], u1f[8], u2f[8];
        unp8(hr[c], hf); unp8(u1r[c], u1f); unp8(u2r[c], u2f);
        #pragma unroll
        for (int j = 0; j < 8; j++) {
            int k = c * 8 + j;
            float hk = hf[j] * rd;
            float wak = Wattn[k];
            th += hk * wak;
            ta += u1f[j] * rd * wak;
            tb += u2f[j] * wak;
            const float4* wr = WR + k * 16 + sub * 4;
            fma4(racc[0], hk, wr[0]); fma4(racc[1], hk, wr[1]);
            fma4(racc[2], hk, wr[2]); fma4(racc[3], hk, wr[3]);
        }
    }
    float* lr = &ldsres[nl * ML_PAD + sub * 16];
    *(float4*)&lr[0] = racc[0];  *(float4*)&lr[4] = racc[1];
    *(float4*)&lr[8] = racc[2];  *(float4*)&lr[12] = racc[3];
    // ---- softmax coefficients ----
    float ba = battn[0];
    float s0 = 0.75f * th + 1.5f * ta + 0.75f * tb + ba;
    float s1 = 1.5f * th - 1.5f * tb + ba;
    float s2 = 0.75f * th - 1.5f * ta + 0.75f * tb + ba;
    float mx = fmaxf(s0, fmaxf(s1, s2));
    float e0 = expf(s0 - mx), e1 = expf(s1 - mx), e2 = expf(s2 - mx);
    float inv = 1.f / (e0 + e1 + e2);
    float w0 = e0 * inv, w1 = e1 * inv, w2 = e2 * inv;
    float ca = 0.75f * w0 + 1.5f * w1 + 0.75f * w2;
    float cb = 1.5f * (w0 - w2);
    float cc = 0.75f * w0 - 1.5f * w1 + 0.75f * w2;
    // ---- phase 2: t = relu([af | h] @ Wf1 + bf1) slice ----
    const float4* WF1 = (const float4*)Wf1;
    const float4* BF1 = (const float4*)bf1 + sub * 4;
    float4 tacc[4] = {BF1[0], BF1[1], BF1[2], BF1[3]};
    #pragma unroll 2
    for (int c = 0; c < 8; c++) {
        float hf[8], u1f[8], u2f[8];
        unp8(hr[c], hf); unp8(u1r[c], u1f); unp8(u2r[c], u2f);
        #pragma unroll
        for (int j = 0; j < 8; j++) {
            int k = c * 8 + j;
            float hk = hf[j] * rd;
            float af = ca * hk + cb * (u1f[j] * rd) + cc * u2f[j];
            const float4* wa = WF1 + k * 16 + sub * 4;
            const float4* wh = WF1 + (64 + k) * 16 + sub * 4;
            fma4(tacc[0], af, wa[0]); fma4(tacc[1], af, wa[1]);
            fma4(tacc[2], af, wa[2]); fma4(tacc[3], af, wa[3]);
            fma4(tacc[0], hk, wh[0]); fma4(tacc[1], hk, wh[1]);
            fma4(tacc[2], hk, wh[2]); fma4(tacc[3], hk, wh[3]);
        }
    }
    const float4* WF2 = (const float4*)Wf2 + sub * 4;
    float fwp = 0.f;
    #pragma unroll
    for (int i = 0; i < 4; i++) {
        float4 v = tacc[i];
        v.x = fmaxf(v.x, 0.f); v.y = fmaxf(v.y, 0.f);
        v.z = fmaxf(v.z, 0.f); v.w = fmaxf(v.w, 0.f);
        float4 w = WF2[i];
        fwp += v.x * w.x + v.y * w.y + v.z * w.z + v.w * w.w;
    }
    fwp += __shfl_xor(fwp, 1, 64);
    fwp += __shfl_xor(fwp, 2, 64);
    float fw = 1.f / (1.f + expf(-(fwp + bf2[0])));
    float c_af = 0.1f * fw, c_mf = 1.f - fw;
    __syncthreads();   // res rows complete
    // ---- phase 3: g = relu(fused @ W3 + b3) slice ----
    const float4* W34 = (const float4*)W3;
    const float4* B3 = (const float4*)b3 + sub * 4;
    float4 gacc[4] = {B3[0], B3[1], B3[2], B3[3]};
    const float* lrow = &ldsres[nl * ML_PAD];
    #pragma unroll 2
    for (int c = 0; c < 8; c++) {
        float hf[8], u1f[8], u2f[8];
        unp8(hr[c], hf); unp8(u1r[c], u1f); unp8(u2r[c], u2f);
        #pragma unroll
        for (int j = 0; j < 8; j++) {
            int k = c * 8 + j;
            float hk = hf[j] * rd;
            float af = ca * hk + cb * (u1f[j] * rd) + cc * u2f[j];
            float f = c_af * af + c_mf * hk + 0.8f * lrow[k];
            const float4* wr = W34 + k * 16 + sub * 4;
            fma4(gacc[0], f, wr[0]); fma4(gacc[1], f, wr[1]);
            fma4(gacc[2], f, wr[2]); fma4(gacc[3], f, wr[3]);
        }
    }
    const float2* W42 = (const float2*)W4 + sub * 16;
    float l0 = 0.f, l1 = 0.f;
    #pragma unroll
    for (int i = 0; i < 4; i++) {
        float4 v = gacc[i];
        v.x = fmaxf(v.x, 0.f); v.y = fmaxf(v.y, 0.f);
        v.z = fmaxf(v.z, 0.f); v.w = fmaxf(v.w, 0.f);
        float2 wa = W42[i * 4 + 0], wb = W42[i * 4 + 1];
        float2 wc = W42[i * 4 + 2], wd = W42[i * 4 + 3];
        l0 += v.x * wa.x + v.y * wb.x + v.z * wc.x + v.w * wd.x;
        l1 += v.x * wa.y + v.y * wb.y + v.z * wc.y + v.w * wd.y;
    }
    l0 += __shfl_xor(l0, 1, 64); l0 += __shfl_xor(l0, 2, 64);
    l1 += __shfl_xor(l1, 1, 64); l1 += __shfl_xor(l1, 2, 64);
    if (act && sub == 0) out[n] = make_float2(l0 + b4[0], l1 + b4[1]);
}

// ----------------------------- launch --------------------------------------

extern "C" void kernel_launch(void* const* d_in, const int* in_sizes, int n_in,
                              void* d_out, int out_size, void* d_ws, size_t ws_size,
                              hipStream_t stream) {
    const float* in_feat = (const float*)d_in[0];
    const int*   src     = (const int*)d_in[1];
    const int*   dst     = (const int*)d_in[2];
    const float* W1   = (const float*)d_in[3];
    const float* b1   = (const float*)d_in[4];
    const float* W2   = (const float*)d_in[5];
    const float* b2   = (const float*)d_in[6];
    const float* Wres = (const float*)d_in[7];
    const float* bres = (const float*)d_in[8];
    const float* Wattn = (const float*)d_in[9];
    const float* battn = (const float*)d_in[10];
    const float* Wf1  = (const float*)d_in[11];
    const float* bf1  = (const float*)d_in[12];
    const float* Wf2  = (const float*)d_in[13];
    const float* bf2  = (const float*)d_in[14];
    const float* W3   = (const float*)d_in[15];
    const float* b3   = (const float*)d_in[16];
    const float* W4   = (const float*)d_in[17];
    const float* b4   = (const float*)d_in[18];

    const int N = in_sizes[0] / 128;
    const int E = in_sizes[1];
    const int B = (N + BNODES - 1) >> BSHIFT;

    char* p = (char*)d_ws;
    auto take = [&](size_t bytes) -> char* {
        char* r = p;
        p += (bytes + 255) & ~(size_t)255;
        return r;
    };
    int*   bucketCount  = (int*)take((size_t)(B + 1) * 4);
    int*   bucketPtr    = (int*)take((size_t)(B + 1) * 4);
    int*   bucketCursor = (int*)take((size_t)(B + 1) * 4);
    int*   rowPtr       = (int*)take((size_t)(N + 1) * 4);
    float* dinv         = (float*)take((size_t)N * 4);
    float* rdeg         = (float*)take((size_t)N * 4);
    int*   srcSorted    = (int*)take((size_t)E * 4);
    float* h1     = (float*)take((size_t)N * 256);
    float4* hs16  = (float4*)take((size_t)N * 128);
    float4* u1s16 = (float4*)take((size_t)N * 128);
    float4* u2s16 = (float4*)take((size_t)N * 128);
    int*   ebuf = (int*)h1;   // dead before dense1 writes h1 (stream order)

    int eb = (E + CHUNK - 1) / CHUNK;
    int qb = ((N * 4) + 255) / 256;     // 4 thr/node kernels
    int spb = (N * 64 + 255) / 256;     // wave/node kernels

    hipMemsetAsync(bucketCount, 0, (size_t)B * 4, stream);
    bucket_count_k<<<eb, 256, 0, stream>>>(dst, bucketCount, E, B);
    bucket_scan_k<<<1, 64, 0, stream>>>(bucketCount, bucketPtr, bucketCursor,
                                        rowPtr, B, N, E);
    bucket_scatter_k<<<eb, 256, 0, stream>>>(src, dst, bucketCursor, ebuf, E, B);
    csr_build_k<<<B, 256, 0, stream>>>(ebuf, bucketPtr, rowPtr, dinv, rdeg,
                                       srcSorted, N);

    dense1_k<<<qb, 256, 0, stream>>>(in_feat, W1, b1, h1, N);
    dense2_k<<<qb, 256, 0, stream>>>(h1, W2, b2, dinv, hs16, N);

    spmm_k<true><<<spb, 256, 0, stream>>>(hs16, srcSorted, rowPtr, dinv,
                                          u1s16, N);
    spmm_k<false><<<spb, 256, 0, stream>>>(u1s16, srcSorted, rowPtr, dinv,
                                           u2s16, N);

    mlp_k<<<qb, 256, 0, stream>>>(hs16, u1s16, u2s16, rdeg,
                                  Wattn, battn, Wres, bres,
                                  Wf1, bf1, Wf2, bf2, W3, b3, W4, b4,
                                  (float2*)d_out, N);
}

// Round 8
// 448.282 us; speedup vs baseline: 1.4444x; 1.4444x over previous
//
#include <hip/hip_runtime.h>
#include <hip/hip_fp16.h>
#include <math.h>

// ---------------------------------------------------------------------------
// ADCGNN amazon: N=50000, E=1.6M, IN=128, H=64, C=2, K=3
// Structure = R6 (best: 432 us) + one fix: tail GEMV weights (Wf1, W3) are
// pre-converted to fp16 TRANSPOSED (w[j][k], 24 KB total -> L1-resident,
// per-lane contiguous float4 column loads). R4/R6 evidence: tail was stalled
// on a 48 KB fp32 L2 weight stream with per-iter dependent loads.
//
//   build: bucket_count -> bucket_scan -> bucket_scatter -> csr_build
//   conv:  wf1t/w3t fp16 transposed weight tables (runs first, independent)
//   dense1:    h1 = relu(X@W1+b1)                  (thread/node fp32 AoS)
//   dense2res: hs16 = relu(h1@W2+b2)*dinv (fp16), res fp32, th = h.Wattn
//   spmm:      u1s16 = dinv^2*(A^T hs) (fp16), ta = u1.Wattn
//   tail:      wave/node: gather u2 (LDS only) -> softmax -> Wf1/Wf2 ->
//              W3 -> W4 -> logits  (weights via fp16 transposed columns)
// ---------------------------------------------------------------------------

#define BSHIFT 7
#define BNODES 128
#define BMAX   512
#define EPT    32
#define CHUNK  (256 * EPT)
#define CAP    8192

__device__ __forceinline__ void fma4(float4& acc, float s, const float4 w) {
    acc.x += s * w.x; acc.y += s * w.y; acc.z += s * w.z; acc.w += s * w.w;
}
__device__ __forceinline__ void acc_h8(float4& a, float4& b, const float4 v) {
    const __half2* hp = (const __half2*)&v;
    float2 f0 = __half22float2(hp[0]);
    float2 f1 = __half22float2(hp[1]);
    float2 f2 = __half22float2(hp[2]);
    float2 f3 = __half22float2(hp[3]);
    a.x += f0.x; a.y += f0.y; a.z += f1.x; a.w += f1.y;
    b.x += f2.x; b.y += f2.y; b.z += f3.x; b.w += f3.y;
}
__device__ __forceinline__ float4 pack_h8(const float* v, float s) {
    float4 o;
    __half2* hp = (__half2*)&o;
    hp[0] = __floats2half2_rn(v[0] * s, v[1] * s);
    hp[1] = __floats2half2_rn(v[2] * s, v[3] * s);
    hp[2] = __floats2half2_rn(v[4] * s, v[5] * s);
    hp[3] = __floats2half2_rn(v[6] * s, v[7] * s);
    return o;
}
__device__ __forceinline__ void unp8(const float4 v, float* f) {
    const __half2* hp = (const __half2*)&v;
    float2 a = __half22float2(hp[0]); f[0] = a.x; f[1] = a.y;
    float2 b = __half22float2(hp[1]); f[2] = b.x; f[3] = b.y;
    float2 c = __half22float2(hp[2]); f[4] = c.x; f[5] = c.y;
    float2 d = __half22float2(hp[3]); f[6] = d.x; f[7] = d.y;
}

// ----------------------------- weight conversion ---------------------------
// wf1t[j*128+k] = Wf1[k*64+j] (fp16), w3t[j*64+k] = W3[k*64+j] (fp16)

__global__ __launch_bounds__(256) void conv_k(const float* __restrict__ Wf1,
                                              const float* __restrict__ W3,
                                              __half* __restrict__ wf1t,
                                              __half* __restrict__ w3t) {
    int t = blockIdx.x * 256 + threadIdx.x;
    if (t < 64 * 128) {
        int j = t >> 7, k = t & 127;
        wf1t[t] = __float2half(Wf1[k * 64 + j]);
    }
    if (t < 64 * 64) {
        int j = t >> 6, k = t & 63;
        w3t[t] = __float2half(W3[k * 64 + j]);
    }
}

// ----------------------------- graph build ---------------------------------

__global__ __launch_bounds__(256) void bucket_count_k(const int* __restrict__ dst,
                                                      int* __restrict__ bucketCount,
                                                      int E, int B) {
    __shared__ int cnt[BMAX];
    for (int i = threadIdx.x; i < B; i += 256) cnt[i] = 0;
    __syncthreads();
    int base = blockIdx.x * CHUNK;
    #pragma unroll
    for (int t = 0; t < EPT; t++) {
        int e = base + t * 256 + threadIdx.x;
        if (e < E) atomicAdd(&cnt[dst[e] >> BSHIFT], 1);
    }
    __syncthreads();
    for (int i = threadIdx.x; i < B; i += 256)
        if (cnt[i] > 0) atomicAdd(&bucketCount[i], cnt[i]);
}

__global__ __launch_bounds__(64) void bucket_scan_k(const int* __restrict__ bucketCount,
                                                    int* __restrict__ bucketPtr,
                                                    int* __restrict__ bucketCursor,
                                                    int* __restrict__ rowPtr,
                                                    int B, int N, int E) {
    int lane = threadIdx.x;
    const int PT = (BMAX + 63) / 64;
    int v[PT]; int s = 0;
    #pragma unroll
    for (int t = 0; t < PT; t++) {
        int i = lane * PT + t;
        v[t] = (i < B) ? bucketCount[i] : 0;
        s += v[t];
    }
    int x = s;
    #pragma unroll
    for (int off = 1; off < 64; off <<= 1) {
        int y = __shfl_up(x, off, 64);
        if (lane >= off) x += y;
    }
    int run = x - s;
    #pragma unroll
    for (int t = 0; t < PT; t++) {
        int i = lane * PT + t;
        if (i < B) { bucketPtr[i] = run; bucketCursor[i] = run; }
        run += v[t];
    }
    if (lane == 63) bucketPtr[B] = x;
    if (lane == 0) rowPtr[N] = E;
}

__global__ __launch_bounds__(256) void bucket_scatter_k(const int* __restrict__ src,
                                                        const int* __restrict__ dst,
                                                        int* __restrict__ bucketCursor,
                                                        int* __restrict__ ebuf,
                                                        int E, int B) {
    __shared__ int cnt[BMAX];
    __shared__ int base[BMAX];
    __shared__ int cur[BMAX];
    for (int i = threadIdx.x; i < B; i += 256) { cnt[i] = 0; cur[i] = 0; }
    __syncthreads();
    int cbase = blockIdx.x * CHUNK;
    int d[EPT];
    #pragma unroll
    for (int t = 0; t < EPT; t++) {
        int e = cbase + t * 256 + threadIdx.x;
        d[t] = (e < E) ? dst[e] : -1;
        if (d[t] >= 0) atomicAdd(&cnt[d[t] >> BSHIFT], 1);
    }
    __syncthreads();
    for (int i = threadIdx.x; i < B; i += 256)
        if (cnt[i] > 0) base[i] = atomicAdd(&bucketCursor[i], cnt[i]);
    __syncthreads();
    #pragma unroll
    for (int t = 0; t < EPT; t++) {
        int e = cbase + t * 256 + threadIdx.x;
        if (d[t] >= 0) {
            int b = d[t] >> BSHIFT;
            int c = atomicAdd(&cur[b], 1);
            int pack = (src[e] & 0xFFFF) | ((d[t] & (BNODES - 1)) << 16);
            ebuf[base[b] + c] = pack;
        }
    }
}

__global__ __launch_bounds__(256) void csr_build_k(const int* __restrict__ ebuf,
                                                   const int* __restrict__ bucketPtr,
                                                   int* __restrict__ rowPtr,
                                                   float* __restrict__ dinv,
                                                   float* __restrict__ rdeg,
                                                   int* __restrict__ srcSorted,
                                                   int N) {
    __shared__ int deg[BNODES];
    __shared__ int rp[BNODES + 1];
    __shared__ int cur[BNODES];
    __shared__ int stage[CAP];
    int b = blockIdx.x;
    int nodeBase = b << BSHIFT;
    int nNodes = min(BNODES, N - nodeBase);
    int eBase = bucketPtr[b];
    int eCnt = bucketPtr[b + 1] - eBase;
    for (int i = threadIdx.x; i < BNODES; i += 256) deg[i] = 0;
    __syncthreads();
    for (int i = threadIdx.x; i < eCnt; i += 256)
        atomicAdd(&deg[(ebuf[eBase + i] >> 16) & (BNODES - 1)], 1);
    __syncthreads();
    if (threadIdx.x < 64) {
        int lane = threadIdx.x;
        int d0 = deg[2 * lane], d1 = deg[2 * lane + 1];
        int s = d0 + d1;
        int x = s;
        #pragma unroll
        for (int off = 1; off < 64; off <<= 1) {
            int y = __shfl_up(x, off, 64);
            if (lane >= off) x += y;
        }
        int ex = x - s;
        rp[2 * lane] = ex;
        rp[2 * lane + 1] = ex + d0;
        cur[2 * lane] = ex;
        cur[2 * lane + 1] = ex + d0;
        if (lane == 63) rp[BNODES] = x;
    }
    __syncthreads();
    for (int j = threadIdx.x; j < nNodes; j += 256) {
        rowPtr[nodeBase + j] = eBase + rp[j];
        int dg = deg[j];
        float d = (float)(dg > 1 ? dg : 1);
        dinv[nodeBase + j] = rsqrtf(d);
        rdeg[nodeBase + j] = sqrtf(d);
    }
    if (eCnt <= CAP) {
        for (int i = threadIdx.x; i < eCnt; i += 256) {
            int p = ebuf[eBase + i];
            int ld = (p >> 16) & (BNODES - 1);
            int pos = atomicAdd(&cur[ld], 1);
            stage[pos] = p & 0xFFFF;
        }
        __syncthreads();
        for (int i = threadIdx.x; i < eCnt; i += 256)
            srcSorted[eBase + i] = stage[i];
    } else {
        for (int i = threadIdx.x; i < eCnt; i += 256) {
            int p = ebuf[eBase + i];
            int ld = (p >> 16) & (BNODES - 1);
            int pos = atomicAdd(&cur[ld], 1);
            srcSorted[eBase + pos] = p & 0xFFFF;
        }
    }
}

// ----------------------------- dense1 --------------------------------------

#define D1_BLK 128
#define D1_PAD 68

__global__ __launch_bounds__(D1_BLK) void dense1_k(const float* __restrict__ Xg,
                                                   const float* __restrict__ W1,
                                                   const float* __restrict__ b1,
                                                   float* __restrict__ h1, int N) {
    __shared__ float lds[D1_BLK * D1_PAD];
    int n0 = blockIdx.x * D1_BLK;
    int n = n0 + threadIdx.x;
    bool act = (n < N);
    const float4* W = (const float4*)W1;
    const float4* B = (const float4*)b1;
    float4 acc[16];
    #pragma unroll
    for (int j = 0; j < 16; j++) acc[j] = B[j];
    if (act) {
        const float4* X = (const float4*)Xg + (size_t)n * 32;
        float4 a = X[0];
        #pragma unroll 1
        for (int kc = 0; kc < 32; kc++) {
            float4 an = a;
            if (kc + 1 < 32) an = X[kc + 1];
            const float4* wrow = W + kc * 64;
            #pragma unroll
            for (int j = 0; j < 16; j++) {
                fma4(acc[j], a.x, wrow[j]);
                fma4(acc[j], a.y, wrow[16 + j]);
                fma4(acc[j], a.z, wrow[32 + j]);
                fma4(acc[j], a.w, wrow[48 + j]);
            }
            a = an;
        }
    }
    float* myrow = &lds[threadIdx.x * D1_PAD];
    #pragma unroll
    for (int j = 0; j < 16; j++) {
        float4 v = acc[j];
        *(float4*)&myrow[4 * j] = make_float4(fmaxf(v.x, 0.f), fmaxf(v.y, 0.f),
                                              fmaxf(v.z, 0.f), fmaxf(v.w, 0.f));
    }
    __syncthreads();
    float4* o4 = (float4*)h1;
    #pragma unroll
    for (int r = 0; r < 16; r++) {
        int idx = r * D1_BLK + threadIdx.x;
        int row = idx >> 4, col = idx & 15;
        int gn = n0 + row;
        if (gn < N) o4[(size_t)gn * 16 + col] = *(float4*)&lds[row * D1_PAD + col * 4];
    }
}

// ----------------------------- dense2res -----------------------------------

#define D2_BLK 128
#define D2_PAD 68

__global__ __launch_bounds__(D2_BLK) void dense2res_k(const float* __restrict__ h1,
                                                      const float* __restrict__ W2,
                                                      const float* __restrict__ b2,
                                                      const float* __restrict__ Wres,
                                                      const float* __restrict__ bres,
                                                      const float* __restrict__ Wattn,
                                                      const float* __restrict__ dinv,
                                                      float4* __restrict__ hs16,
                                                      float* __restrict__ resg,
                                                      float* __restrict__ thv, int N) {
    __shared__ float lds[D2_BLK * D2_PAD];
    int n0 = blockIdx.x * D2_BLK;
    int n = n0 + threadIdx.x;
    bool act = (n < N);
    const float4* W = (const float4*)W2;
    const float4* B = (const float4*)b2;
    float4 acc[16];
    #pragma unroll
    for (int j = 0; j < 16; j++) acc[j] = B[j];
    if (act) {
        const float4* X = (const float4*)h1 + (size_t)n * 16;
        float4 a = X[0];
        #pragma unroll 1
        for (int kc = 0; kc < 16; kc++) {
            float4 an = a;
            if (kc + 1 < 16) an = X[kc + 1];
            const float4* wrow = W + kc * 64;
            #pragma unroll
            for (int j = 0; j < 16; j++) {
                fma4(acc[j], a.x, wrow[j]);
                fma4(acc[j], a.y, wrow[16 + j]);
                fma4(acc[j], a.z, wrow[32 + j]);
                fma4(acc[j], a.w, wrow[48 + j]);
            }
            a = an;
        }
    }
    const float4* Wa = (const float4*)Wattn;
    float th = 0.f;
    float* myrow = &lds[threadIdx.x * D2_PAD];
    #pragma unroll
    for (int j = 0; j < 16; j++) {
        float4 v = acc[j];
        v.x = fmaxf(v.x, 0.f); v.y = fmaxf(v.y, 0.f);
        v.z = fmaxf(v.z, 0.f); v.w = fmaxf(v.w, 0.f);
        acc[j] = v;
        *(float4*)&myrow[4 * j] = v;
        float4 w = Wa[j];
        th += v.x * w.x + v.y * w.y + v.z * w.z + v.w * w.w;
    }
    if (act) thv[n] = th;
    __syncthreads();
    #pragma unroll
    for (int r = 0; r < 8; r++) {
        int idx = r * D2_BLK + threadIdx.x;
        int row = idx >> 3, col = idx & 7;
        int gn = n0 + row;
        if (gn < N) {
            float di = dinv[gn];
            hs16[(size_t)gn * 8 + col] = pack_h8(&lds[row * D2_PAD + col * 8], di);
        }
    }
    const float4* WR = (const float4*)Wres;
    const float4* BR = (const float4*)bres;
    float4 acc2[16];
    #pragma unroll
    for (int j = 0; j < 16; j++) acc2[j] = BR[j];
    #pragma unroll 1
    for (int kc = 0; kc < 16; kc++) {
        float4 a2 = acc[kc];
        const float4* wrow = WR + kc * 64;
        #pragma unroll
        for (int j = 0; j < 16; j++) {
            fma4(acc2[j], a2.x, wrow[j]);
            fma4(acc2[j], a2.y, wrow[16 + j]);
            fma4(acc2[j], a2.z, wrow[32 + j]);
            fma4(acc2[j], a2.w, wrow[48 + j]);
        }
    }
    __syncthreads();
    #pragma unroll
    for (int j = 0; j < 16; j++) *(float4*)&myrow[4 * j] = acc2[j];
    __syncthreads();
    float4* r4 = (float4*)resg;
    #pragma unroll
    for (int r = 0; r < 16; r++) {
        int idx = r * D2_BLK + threadIdx.x;
        int row = idx >> 4, col = idx & 15;
        int gn = n0 + row;
        if (gn < N) r4[(size_t)gn * 16 + col] = *(float4*)&lds[row * D2_PAD + col * 4];
    }
}

// ----------------------------- SPMM (fp16 gather) --------------------------

__global__ __launch_bounds__(256) void spmm_k(const float4* __restrict__ xs16,
                                              const int* __restrict__ srcs,
                                              const int* __restrict__ rowPtr,
                                              const float* __restrict__ dinv,
                                              const float* __restrict__ Wattn,
                                              float4* __restrict__ u1s16,
                                              float* __restrict__ tav, int N) {
    int node = (blockIdx.x * 256 + threadIdx.x) >> 6;
    if (node >= N) return;
    int lane = threadIdx.x & 63;
    int sub = lane >> 3, q = lane & 7;
    int s0 = rowPtr[node], s1 = rowPtr[node + 1];
    float4 z = make_float4(0.f, 0.f, 0.f, 0.f);
    float4 a0 = z, a1 = z, b0 = z, b1 = z, c0 = z, c1 = z, d0 = z, d1 = z;
    int i = s0 + sub;
    for (; i + 24 < s1; i += 32) {
        float4 vA = xs16[(size_t)srcs[i] * 8 + q];
        float4 vB = xs16[(size_t)srcs[i + 8] * 8 + q];
        float4 vC = xs16[(size_t)srcs[i + 16] * 8 + q];
        float4 vD = xs16[(size_t)srcs[i + 24] * 8 + q];
        acc_h8(a0, a1, vA); acc_h8(b0, b1, vB);
        acc_h8(c0, c1, vC); acc_h8(d0, d1, vD);
    }
    for (; i < s1; i += 8) {
        float4 v = xs16[(size_t)srcs[i] * 8 + q];
        acc_h8(a0, a1, v);
    }
    a0.x += b0.x + c0.x + d0.x; a0.y += b0.y + c0.y + d0.y;
    a0.z += b0.z + c0.z + d0.z; a0.w += b0.w + c0.w + d0.w;
    a1.x += b1.x + c1.x + d1.x; a1.y += b1.y + c1.y + d1.y;
    a1.z += b1.z + c1.z + d1.z; a1.w += b1.w + c1.w + d1.w;
    #pragma unroll
    for (int m = 8; m < 64; m <<= 1) {
        a0.x += __shfl_xor(a0.x, m, 64); a0.y += __shfl_xor(a0.y, m, 64);
        a0.z += __shfl_xor(a0.z, m, 64); a0.w += __shfl_xor(a0.w, m, 64);
        a1.x += __shfl_xor(a1.x, m, 64); a1.y += __shfl_xor(a1.y, m, 64);
        a1.z += __shfl_xor(a1.z, m, 64); a1.w += __shfl_xor(a1.w, m, 64);
    }
    float ta = 0.f;
    if (sub == 0) {
        float di = dinv[node];
        float di2 = di * di;
        float f[8] = {a0.x, a0.y, a0.z, a0.w, a1.x, a1.y, a1.z, a1.w};
        u1s16[(size_t)node * 8 + q] = pack_h8(f, di2);
        #pragma unroll
        for (int j = 0; j < 8; j++) ta += f[j] * di * Wattn[q * 8 + j];
    }
    ta += __shfl_xor(ta, 1, 64);
    ta += __shfl_xor(ta, 2, 64);
    ta += __shfl_xor(ta, 4, 64);
    if (lane == 0) tav[node] = ta;
}

// ----------------------------- fused spmm2 + tail --------------------------
// Wave per node. GEMV weights: fp16 transposed columns (24 KB, L1-resident),
// per-lane contiguous float4 loads; broadcast inputs via readlane (__shfl).

#define TL_PAD 72

__global__ __launch_bounds__(256) void tail_k(const float4* __restrict__ u1s16,
                                              const int* __restrict__ srcs,
                                              const int* __restrict__ rowPtr,
                                              const float* __restrict__ dinv,
                                              const float* __restrict__ rdeg,
                                              const __half* __restrict__ hs16h,
                                              const __half* __restrict__ u1s16h,
                                              const float* __restrict__ resg,
                                              const float* __restrict__ thv,
                                              const float* __restrict__ tav,
                                              const __half* __restrict__ wf1t,
                                              const __half* __restrict__ w3t,
                                              const float* __restrict__ Wattn,
                                              const float* __restrict__ battn,
                                              const float* __restrict__ bf1,
                                              const float* __restrict__ Wf2,
                                              const float* __restrict__ bf2,
                                              const float* __restrict__ b3,
                                              const float* __restrict__ W4,
                                              const float* __restrict__ b4,
                                              float2* __restrict__ out, int N) {
    __shared__ float lds[4 * TL_PAD];
    int w = threadIdx.x >> 6;
    int lane = threadIdx.x & 63;
    int node = blockIdx.x * 4 + w;
    bool active = (node < N);
    int sub = lane >> 3, q = lane & 7;
    if (active) {
        int s0 = rowPtr[node], s1 = rowPtr[node + 1];
        float4 z = make_float4(0.f, 0.f, 0.f, 0.f);
        float4 a0 = z, a1 = z, b0 = z, b1 = z, c0 = z, c1 = z, d0 = z, d1 = z;
        int i = s0 + sub;
        for (; i + 24 < s1; i += 32) {
            float4 vA = u1s16[(size_t)srcs[i] * 8 + q];
            float4 vB = u1s16[(size_t)srcs[i + 8] * 8 + q];
            float4 vC = u1s16[(size_t)srcs[i + 16] * 8 + q];
            float4 vD = u1s16[(size_t)srcs[i + 24] * 8 + q];
            acc_h8(a0, a1, vA); acc_h8(b0, b1, vB);
            acc_h8(c0, c1, vC); acc_h8(d0, d1, vD);
        }
        for (; i < s1; i += 8) {
            float4 v = u1s16[(size_t)srcs[i] * 8 + q];
            acc_h8(a0, a1, v);
        }
        a0.x += b0.x + c0.x + d0.x; a0.y += b0.y + c0.y + d0.y;
        a0.z += b0.z + c0.z + d0.z; a0.w += b0.w + c0.w + d0.w;
        a1.x += b1.x + c1.x + d1.x; a1.y += b1.y + c1.y + d1.y;
        a1.z += b1.z + c1.z + d1.z; a1.w += b1.w + c1.w + d1.w;
        #pragma unroll
        for (int m = 8; m < 64; m <<= 1) {
            a0.x += __shfl_xor(a0.x, m, 64); a0.y += __shfl_xor(a0.y, m, 64);
            a0.z += __shfl_xor(a0.z, m, 64); a0.w += __shfl_xor(a0.w, m, 64);
            a1.x += __shfl_xor(a1.x, m, 64); a1.y += __shfl_xor(a1.y, m, 64);
            a1.z += __shfl_xor(a1.z, m, 64); a1.w += __shfl_xor(a1.w, m, 64);
        }
        if (sub == 0) {
            float di = dinv[node];
            float* row = &lds[w * TL_PAD + q * 8];
            row[0] = a0.x * di; row[1] = a0.y * di;
            row[2] = a0.z * di; row[3] = a0.w * di;
            row[4] = a1.x * di; row[5] = a1.y * di;
            row[6] = a1.z * di; row[7] = a1.w * di;
        }
    }
    __syncthreads();
    if (!active) return;
    float u2j = lds[w * TL_PAD + lane];
    float rd = rdeg[node];
    float hj = __half2float(hs16h[(size_t)node * 64 + lane]) * rd;
    float u1j = __half2float(u1s16h[(size_t)node * 64 + lane]) * rd;
    float resj = resg[(size_t)node * 64 + lane];
    float tb = u2j * Wattn[lane];
    #pragma unroll
    for (int m = 1; m < 64; m <<= 1) tb += __shfl_xor(tb, m, 64);
    float th = thv[node], ta = tav[node], ba = battn[0];
    float s0 = 0.75f * th + 1.5f * ta + 0.75f * tb + ba;
    float s1 = 1.5f * th - 1.5f * tb + ba;
    float s2 = 0.75f * th - 1.5f * ta + 0.75f * tb + ba;
    float mx = fmaxf(s0, fmaxf(s1, s2));
    float e0 = expf(s0 - mx), e1 = expf(s1 - mx), e2 = expf(s2 - mx);
    float inv = 1.f / (e0 + e1 + e2);
    float w0 = e0 * inv, w1 = e1 * inv, w2 = e2 * inv;
    float ca = 0.75f * w0 + 1.5f * w1 + 0.75f * w2;
    float cb = 1.5f * (w0 - w2);
    float cc = 0.75f * w0 - 1.5f * w1 + 0.75f * w2;
    float afj = ca * hj + cb * u1j + cc * u2j;
    // t = relu([af | h] @ Wf1 + bf1): lane's fp16 column = 128 halves (256 B)
    const float4* wf1c = (const float4*)(wf1t + (size_t)lane * 128);
    float t = bf1[lane];
    #pragma unroll
    for (int c = 0; c < 8; c++) {          // af part, k = c*8+j
        float wf[8]; unp8(wf1c[c], wf);
        #pragma unroll
        for (int j = 0; j < 8; j++)
            t += __shfl(afj, c * 8 + j, 64) * wf[j];
    }
    #pragma unroll
    for (int c = 0; c < 8; c++) {          // h part, k = 64 + c*8+j
        float wf[8]; unp8(wf1c[8 + c], wf);
        #pragma unroll
        for (int j = 0; j < 8; j++)
            t += __shfl(hj, c * 8 + j, 64) * wf[j];
    }
    t = fmaxf(t, 0.f);
    float fwacc = t * Wf2[lane];
    #pragma unroll
    for (int m = 1; m < 64; m <<= 1) fwacc += __shfl_xor(fwacc, m, 64);
    float fw = 1.f / (1.f + expf(-(fwacc + bf2[0])));
    float fj = 0.1f * fw * afj + (1.f - fw) * hj + 0.8f * resj;
    // g = relu(fused @ W3 + b3): lane's fp16 column = 64 halves (128 B)
    const float4* w3c = (const float4*)(w3t + (size_t)lane * 64);
    float g = b3[lane];
    #pragma unroll
    for (int c = 0; c < 8; c++) {
        float wf[8]; unp8(w3c[c], wf);
        #pragma unroll
        for (int j = 0; j < 8; j++)
            g += __shfl(fj, c * 8 + j, 64) * wf[j];
    }
    g = fmaxf(g, 0.f);
    float2 w4 = ((const float2*)W4)[lane];
    float l0 = g * w4.x, l1 = g * w4.y;
    #pragma unroll
    for (int m = 1; m < 64; m <<= 1) {
        l0 += __shfl_xor(l0, m, 64);
        l1 += __shfl_xor(l1, m, 64);
    }
    if (lane == 0) out[node] = make_float2(l0 + b4[0], l1 + b4[1]);
}

// ----------------------------- launch --------------------------------------

extern "C" void kernel_launch(void* const* d_in, const int* in_sizes, int n_in,
                              void* d_out, int out_size, void* d_ws, size_t ws_size,
                              hipStream_t stream) {
    const float* in_feat = (const float*)d_in[0];
    const int*   src     = (const int*)d_in[1];
    const int*   dst     = (const int*)d_in[2];
    const float* W1   = (const float*)d_in[3];
    const float* b1   = (const float*)d_in[4];
    const float* W2   = (const float*)d_in[5];
    const float* b2   = (const float*)d_in[6];
    const float* Wres = (const float*)d_in[7];
    const float* bres = (const float*)d_in[8];
    const float* Wattn = (const float*)d_in[9];
    const float* battn = (const float*)d_in[10];
    const float* Wf1  = (const float*)d_in[11];
    const float* bf1  = (const float*)d_in[12];
    const float* Wf2  = (const float*)d_in[13];
    const float* bf2  = (const float*)d_in[14];
    const float* W3   = (const float*)d_in[15];
    const float* b3   = (const float*)d_in[16];
    const float* W4   = (const float*)d_in[17];
    const float* b4   = (const float*)d_in[18];

    const int N = in_sizes[0] / 128;
    const int E = in_sizes[1];
    const int B = (N + BNODES - 1) >> BSHIFT;

    char* p = (char*)d_ws;
    auto take = [&](size_t bytes) -> char* {
        char* r = p;
        p += (bytes + 255) & ~(size_t)255;
        return r;
    };
    int*   bucketCount  = (int*)take((size_t)(B + 1) * 4);
    int*   bucketPtr    = (int*)take((size_t)(B + 1) * 4);
    int*   bucketCursor = (int*)take((size_t)(B + 1) * 4);
    int*   rowPtr       = (int*)take((size_t)(N + 1) * 4);
    float* dinv         = (float*)take((size_t)N * 4);
    float* rdeg         = (float*)take((size_t)N * 4);
    float* thv          = (float*)take((size_t)N * 4);
    float* tav          = (float*)take((size_t)N * 4);
    __half* wf1t        = (__half*)take((size_t)64 * 128 * 2);
    __half* w3t         = (__half*)take((size_t)64 * 64 * 2);
    int*   srcSorted    = (int*)take((size_t)E * 4);
    float* h1    = (float*)take((size_t)N * 256);
    float* res   = (float*)take((size_t)N * 256);
    float4* hs16  = (float4*)take((size_t)N * 128);
    float4* u1s16 = (float4*)take((size_t)N * 128);
    int*   ebuf = (int*)h1;   // dead before dense1 writes h1 (stream order)

    int eb = (E + CHUNK - 1) / CHUNK;
    int d1b = (N + D1_BLK - 1) / D1_BLK;
    int d2b = (N + D2_BLK - 1) / D2_BLK;
    int spb = (N * 64 + 255) / 256;
    int tlb = (N + 3) / 4;

    hipMemsetAsync(bucketCount, 0, (size_t)B * 4, stream);
    conv_k<<<32, 256, 0, stream>>>(Wf1, W3, wf1t, w3t);
    bucket_count_k<<<eb, 256, 0, stream>>>(dst, bucketCount, E, B);
    bucket_scan_k<<<1, 64, 0, stream>>>(bucketCount, bucketPtr, bucketCursor,
                                        rowPtr, B, N, E);
    bucket_scatter_k<<<eb, 256, 0, stream>>>(src, dst, bucketCursor, ebuf, E, B);
    csr_build_k<<<B, 256, 0, stream>>>(ebuf, bucketPtr, rowPtr, dinv, rdeg,
                                       srcSorted, N);

    dense1_k<<<d1b, D1_BLK, 0, stream>>>(in_feat, W1, b1, h1, N);
    dense2res_k<<<d2b, D2_BLK, 0, stream>>>(h1, W2, b2, Wres, bres, Wattn, dinv,
                                            hs16, res, thv, N);

    spmm_k<<<spb, 256, 0, stream>>>(hs16, srcSorted, rowPtr, dinv, Wattn,
                                    u1s16, tav, N);

    tail_k<<<tlb, 256, 0, stream>>>(u1s16, srcSorted, rowPtr, dinv, rdeg,
                                    (const __half*)hs16, (const __half*)u1s16,
                                    res, thv, tav, wf1t, w3t, Wattn, battn,
                                    bf1, Wf2, bf2, b3, W4, b4,
                                    (float2*)d_out, N);
}